// Round 9
// baseline (2134.832 us; speedup 1.0000x reference)
//
#include <hip/hip_runtime.h>

#define BATCH   16
#define NPTS    8192
#define NCH     64
#define NPOINT  1024
#define NSAMPLE 32
#define R2      0.01f

// wave64 max-reduction on u64 key via DPP (verified round 8)
#define DPP_RED_STAGE(CTRL)                                                   \
    {                                                                         \
        int lo = (int)(unsigned)(key & 0xffffffffull);                        \
        int hi = (int)(unsigned)(key >> 32);                                  \
        int mlo = __builtin_amdgcn_update_dpp(lo, lo, CTRL, 0xF, 0xF, false); \
        int mhi = __builtin_amdgcn_update_dpp(hi, hi, CTRL, 0xF, 0xF, false); \
        unsigned long long mk =                                               \
            ((unsigned long long)(unsigned)mhi << 32) | (unsigned)mlo;        \
        if (mk > key) key = mk;                                               \
    }

struct FpsShared {
    float pts[NPTS * 3];                    // 96 KB
    unsigned long long red[2][8];
    float ring_f[2][16][3];
};

// ---------------------------------------------------------------------------
// Kernel 1: blocks 0..15 FPS (512 threads, 16 pts/lane), rest transpose.
// FPS bit-exact vs numpy: scalar _rn ops, first-index tie-break via u64 key.
// ---------------------------------------------------------------------------
__global__ __launch_bounds__(512, 1) void fps_tr_kernel(const float* __restrict__ xyz,
                                                        float* __restrict__ new_xyz,
                                                        const float* __restrict__ feat,
                                                        float* __restrict__ feat_t) {
    __shared__ union { FpsShared fps; float tile[64][65]; } U;
    const int t = threadIdx.x;

    if (blockIdx.x >= BATCH) {
        // ---------------- transpose path (512 threads) ----------------
        const int bidx = blockIdx.x - BATCH;          // b * (NPTS/64) + ntile
        const int b  = bidx >> 7;
        const int n0 = (bidx & 127) << 6;
        const int i  = t & 63, c0 = t >> 6;           // c0 in [0,8)
        const float* src = feat + (size_t)b * NCH * NPTS;
#pragma unroll
        for (int r = 0; r < 8; ++r) {
            int c = c0 + r * 8;
            U.tile[c][i] = src[(size_t)c * NPTS + n0 + i];
        }
        __syncthreads();
        const int cc = t & 63, i0 = t >> 6;
        float* dst = feat_t + ((size_t)b * NPTS + n0) * NCH;
#pragma unroll
        for (int r = 0; r < 8; ++r) {
            int ii = i0 + r * 8;
            dst[(size_t)ii * NCH + cc] = U.tile[cc][ii];
        }
        return;
    }

    // ---------------- FPS path ----------------
    const int b = blockIdx.x;
    const float* g = xyz + (size_t)b * NPTS * 3;
    for (int i = t; i < NPTS * 3; i += 512) U.fps.pts[i] = g[i];
    __syncthreads();

    float px[16], py[16], pz[16], dist[16];
#pragma unroll
    for (int k = 0; k < 16; ++k) {
        const int p = t + (k << 9);
        px[k] = U.fps.pts[3 * p + 0];
        py[k] = U.fps.pts[3 * p + 1];
        pz[k] = U.fps.pts[3 * p + 2];
        dist[k] = 1e10f;
    }

    float fx = U.fps.pts[0], fy = U.fps.pts[1], fz = U.fps.pts[2];
    const int wave = t >> 6;

    for (int it = 0; it < NPOINT; ++it) {
        const int rb = (it >> 4) & 1, sl = it & 15;
        if (t == 0) {
            U.fps.ring_f[rb][sl][0] = fx;
            U.fps.ring_f[rb][sl][1] = fy;
            U.fps.ring_f[rb][sl][2] = fz;
        }
        float bestv = -1.0f; int bestk = 0;
#pragma unroll
        for (int k = 0; k < 16; ++k) {
            float dx = __fsub_rn(px[k], fx);
            float dy = __fsub_rn(py[k], fy);
            float dz = __fsub_rn(pz[k], fz);
            float d  = __fadd_rn(__fadd_rn(__fmul_rn(dx, dx), __fmul_rn(dy, dy)),
                                 __fmul_rn(dz, dz));
            float nd = fminf(dist[k], d);
            dist[k] = nd;
            if (nd > bestv) { bestv = nd; bestk = k; }   // ascending k => first index
        }
        const int besti = t + (bestk << 9);
        unsigned long long key =
            ((unsigned long long)__float_as_uint(bestv) << 32) | (unsigned)(~besti);
        DPP_RED_STAGE(0x111)   // row_shr:1
        DPP_RED_STAGE(0x112)   // row_shr:2
        DPP_RED_STAGE(0x114)   // row_shr:4
        DPP_RED_STAGE(0x118)   // row_shr:8
        DPP_RED_STAGE(0x142)   // row_bcast15
        DPP_RED_STAGE(0x143)   // row_bcast31 -> lane 63 = wave max
        const int par = it & 1;
        if ((t & 63) == 63) U.fps.red[par][wave] = key;
        __syncthreads();

        if ((it & 15) == 15 && t < 48) {
            const int base0 = b * NPOINT + (it & ~15);
            new_xyz[(size_t)(base0 + t / 3) * 3 + (t % 3)] =
                U.fps.ring_f[rb][t / 3][t % 3];
        }

        unsigned long long kk = U.fps.red[par][0];
#pragma unroll
        for (int e = 1; e < 8; ++e) {
            unsigned long long ke = U.fps.red[par][e];
            if (ke > kk) kk = ke;
        }
        const int far = (int)(~(unsigned)kk);
        fx = U.fps.pts[3 * far + 0];
        fy = U.fps.pts[3 * far + 1];
        fz = U.fps.pts[3 * far + 2];
    }
}

// ---------------------------------------------------------------------------
// Kernel 2: BQ + register-tiled MLP + maxpool. Block = 256 thr = 128 columns
// (4 centers). Lane owns cols {l, l+64}. Weights staged transposed [k][o]
// (broadcast b128 fragments); h in LDS [col][67] (stride 67 -> conflict-free).
// ---------------------------------------------------------------------------
struct MlpShared {
    float w1t[67 * 68];      // [k][o], k: 0..63 = feat weights, 64..66 = xyz
    float w2t[64 * 68];
    float w3t[64 * 132];     // [k][o0..127], padded row 132
    float h0[128 * 67];      // [col][k]; later reused as h2 [col][o]
    float h1[128 * 67];
    float b1s[64], b2s[64], b3s[128];
    float cxyz[4][3];
    int   gidx[4][NSAMPLE];
};

__global__ __launch_bounds__(256, 1) void bq_mlp_kernel(const float* __restrict__ xyz,
                                                        const float* __restrict__ feat_t,
                                                        const float* __restrict__ new_xyz,
                                                        const float* __restrict__ W1,
                                                        const float* __restrict__ b1,
                                                        const float* __restrict__ W2,
                                                        const float* __restrict__ b2,
                                                        const float* __restrict__ W3,
                                                        const float* __restrict__ b3,
                                                        float* __restrict__ out_feat) {
    __shared__ MlpShared S;
    const int t = threadIdx.x;
    const int b  = blockIdx.x >> 8;            // 256 blocks per batch
    const int p0 = (blockIdx.x & 255) << 2;    // 4 centers per block

    // ---- stage weights (transposed, k-remapped so h0 = [feats(64); xyz(3)]) ----
    for (int i = t; i < 67 * 64; i += 256) {
        const int o = i / 67, kk = i % 67;
        const int ks = (kk < 3) ? (64 + kk) : (kk - 3);
        S.w1t[ks * 68 + o] = W1[i];
    }
    for (int i = t; i < 64 * 64; i += 256) {
        const int o = i >> 6, k = i & 63;
        S.w2t[k * 68 + o] = W2[i];
    }
    for (int i = t; i < 128 * 64; i += 256) {
        const int o = i >> 6, k = i & 63;
        S.w3t[k * 132 + o] = W3[i];
    }
    if (t < 64)  { S.b1s[t] = b1[t]; S.b2s[t] = b2[t]; }
    if (t < 128) S.b3s[t] = b3[t];
    if (t < 12)
        S.cxyz[t / 3][t % 3] = new_xyz[((size_t)b * NPOINT + p0 + t / 3) * 3 + (t % 3)];
    __syncthreads();

    // ---- ball query: wave wv handles center wv (verified scan) ----
    const int wv = t >> 6, l = t & 63;
    {
        const float* pts = xyz + (size_t)b * NPTS * 3;
        const float cx = S.cxyz[wv][0];
        const float cy = S.cxyz[wv][1];
        const float cz = S.cxyz[wv][2];
        int hits = 0, first = 0;
        for (int j0 = 0; j0 < NPTS; j0 += 64) {
            const int j = j0 + l;
            float x = pts[3 * j], y = pts[3 * j + 1], z = pts[3 * j + 2];
            float dx = __fsub_rn(x, cx), dy = __fsub_rn(y, cy), dz = __fsub_rn(z, cz);
            float d2 = __fadd_rn(__fadd_rn(__fmul_rn(dx, dx), __fmul_rn(dy, dy)),
                                 __fmul_rn(dz, dz));
            const bool pred = d2 < R2;
            const unsigned long long mask = __ballot(pred);
            if (hits == 0 && mask)
                first = j0 + (int)(__ffsll((unsigned long long)mask) - 1);
            if (pred) {
                int slot = hits + (int)__popcll(mask & ((1ull << l) - 1ull));
                if (slot < NSAMPLE) S.gidx[wv][slot] = j;
            }
            hits += (int)__popcll(mask);
            if (hits >= NSAMPLE) break;
        }
        if (hits < NSAMPLE && l >= hits && l < NSAMPLE)
            S.gidx[wv][l] = first;
    }
    __syncthreads();

    // ---- gather: 2 threads per column -> h0[col][0..66] ----
    {
        const int c = t >> 1, half = t & 1;
        const int ci = c >> 5, s = c & 31;
        const int gi = S.gidx[ci][s];
        float* hr = &S.h0[c * 67];
        const float4* fp = (const float4*)(feat_t + ((size_t)b * NPTS + gi) * NCH);
        const int q0 = half * 8;
#pragma unroll
        for (int q = 0; q < 8; ++q) {
            float4 v = fp[q0 + q];
            hr[4 * (q0 + q) + 0] = v.x;
            hr[4 * (q0 + q) + 1] = v.y;
            hr[4 * (q0 + q) + 2] = v.z;
            hr[4 * (q0 + q) + 3] = v.w;
        }
        if (half == 1) {
            const float* pp = xyz + ((size_t)b * NPTS + gi) * 3;
            hr[64] = pp[0] - S.cxyz[ci][0];
            hr[65] = pp[1] - S.cxyz[ci][1];
            hr[66] = pp[2] - S.cxyz[ci][2];
        }
    }
    __syncthreads();

    // ---- Layer 1: K=67, o-strip 16 per wave ----
    {
        const float* h0r0 = &S.h0[l * 67];
        const float* h0r1 = &S.h0[(l + 64) * 67];
        const int o0 = wv << 4;
        float a[16][2];
#pragma unroll
        for (int oo = 0; oo < 16; ++oo) { a[oo][0] = 0.f; a[oo][1] = 0.f; }
        for (int k = 0; k < 67; ++k) {
            const float hc0 = h0r0[k], hc1 = h0r1[k];
            const float4* wr = (const float4*)(&S.w1t[k * 68 + o0]);
#pragma unroll
            for (int m = 0; m < 4; ++m) {
                float4 w = wr[m];
                a[4*m+0][0] = fmaf(w.x, hc0, a[4*m+0][0]);
                a[4*m+0][1] = fmaf(w.x, hc1, a[4*m+0][1]);
                a[4*m+1][0] = fmaf(w.y, hc0, a[4*m+1][0]);
                a[4*m+1][1] = fmaf(w.y, hc1, a[4*m+1][1]);
                a[4*m+2][0] = fmaf(w.z, hc0, a[4*m+2][0]);
                a[4*m+2][1] = fmaf(w.z, hc1, a[4*m+2][1]);
                a[4*m+3][0] = fmaf(w.w, hc0, a[4*m+3][0]);
                a[4*m+3][1] = fmaf(w.w, hc1, a[4*m+3][1]);
            }
        }
#pragma unroll
        for (int oo = 0; oo < 16; ++oo) {
            const int o = o0 + oo;
            const float bb = S.b1s[o];
            S.h1[l * 67 + o]        = fmaxf(a[oo][0] + bb, 0.f);
            S.h1[(l + 64) * 67 + o] = fmaxf(a[oo][1] + bb, 0.f);
        }
    }
    __syncthreads();

    // ---- Layer 2: K=64, o-strip 16; writes h2 into h0 buffer ----
    {
        const float* h1r0 = &S.h1[l * 67];
        const float* h1r1 = &S.h1[(l + 64) * 67];
        const int o0 = wv << 4;
        float a[16][2];
#pragma unroll
        for (int oo = 0; oo < 16; ++oo) { a[oo][0] = 0.f; a[oo][1] = 0.f; }
        for (int k = 0; k < 64; ++k) {
            const float hc0 = h1r0[k], hc1 = h1r1[k];
            const float4* wr = (const float4*)(&S.w2t[k * 68 + o0]);
#pragma unroll
            for (int m = 0; m < 4; ++m) {
                float4 w = wr[m];
                a[4*m+0][0] = fmaf(w.x, hc0, a[4*m+0][0]);
                a[4*m+0][1] = fmaf(w.x, hc1, a[4*m+0][1]);
                a[4*m+1][0] = fmaf(w.y, hc0, a[4*m+1][0]);
                a[4*m+1][1] = fmaf(w.y, hc1, a[4*m+1][1]);
                a[4*m+2][0] = fmaf(w.z, hc0, a[4*m+2][0]);
                a[4*m+2][1] = fmaf(w.z, hc1, a[4*m+2][1]);
                a[4*m+3][0] = fmaf(w.w, hc0, a[4*m+3][0]);
                a[4*m+3][1] = fmaf(w.w, hc1, a[4*m+3][1]);
            }
        }
#pragma unroll
        for (int oo = 0; oo < 16; ++oo) {
            const int o = o0 + oo;
            const float bb = S.b2s[o];
            S.h0[l * 67 + o]        = fmaxf(a[oo][0] + bb, 0.f);
            S.h0[(l + 64) * 67 + o] = fmaxf(a[oo][1] + bb, 0.f);
        }
    }
    __syncthreads();

    // ---- Layer 3: K=64, o-strip 32 per wave + maxpool + store ----
    {
        const float* h2r0 = &S.h0[l * 67];
        const float* h2r1 = &S.h0[(l + 64) * 67];
        const int o0 = wv << 5;
        float a[32][2];
#pragma unroll
        for (int oo = 0; oo < 32; ++oo) { a[oo][0] = 0.f; a[oo][1] = 0.f; }
        for (int k = 0; k < 64; ++k) {
            const float hc0 = h2r0[k], hc1 = h2r1[k];
            const float4* wr = (const float4*)(&S.w3t[k * 132 + o0]);
#pragma unroll
            for (int m = 0; m < 8; ++m) {
                float4 w = wr[m];
                a[4*m+0][0] = fmaf(w.x, hc0, a[4*m+0][0]);
                a[4*m+0][1] = fmaf(w.x, hc1, a[4*m+0][1]);
                a[4*m+1][0] = fmaf(w.y, hc0, a[4*m+1][0]);
                a[4*m+1][1] = fmaf(w.y, hc1, a[4*m+1][1]);
                a[4*m+2][0] = fmaf(w.z, hc0, a[4*m+2][0]);
                a[4*m+2][1] = fmaf(w.z, hc1, a[4*m+2][1]);
                a[4*m+3][0] = fmaf(w.w, hc0, a[4*m+3][0]);
                a[4*m+3][1] = fmaf(w.w, hc1, a[4*m+3][1]);
            }
        }
        // maxpool over the 32 samples of each center (lanes within 32-groups),
        // then lane (l&31)==oo keeps output oo.
        const int s = l & 31;
        float out0 = 0.f, out1 = 0.f;
#pragma unroll
        for (int oo = 0; oo < 32; ++oo) {
            const float bb = S.b3s[o0 + oo];
            float r0 = fmaxf(a[oo][0] + bb, 0.f);
            float r1 = fmaxf(a[oo][1] + bb, 0.f);
#pragma unroll
            for (int m = 1; m < 32; m <<= 1) {
                r0 = fmaxf(r0, __shfl_xor(r0, m, 64));
                r1 = fmaxf(r1, __shfl_xor(r1, m, 64));
            }
            if (s == oo) { out0 = r0; out1 = r1; }
        }
        const int o   = o0 + s;
        const int ci0 = l >> 5;          // cols l      -> centers 0,1
        const int ci1 = 2 + (l >> 5);    // cols l+64   -> centers 2,3
        float* outp = out_feat + ((size_t)b * 128 + o) * NPOINT + p0;
        outp[ci0] = out0;
        outp[ci1] = out1;
    }
}

extern "C" void kernel_launch(void* const* d_in, const int* in_sizes, int n_in,
                              void* d_out, int out_size, void* d_ws, size_t ws_size,
                              hipStream_t stream) {
    const float* xyz  = (const float*)d_in[0];
    const float* feat = (const float*)d_in[1];
    const float* W1   = (const float*)d_in[2];
    const float* b1   = (const float*)d_in[3];
    const float* W2   = (const float*)d_in[4];
    const float* b2   = (const float*)d_in[5];
    const float* W3   = (const float*)d_in[6];
    const float* b3   = (const float*)d_in[7];

    float* new_xyz  = (float*)d_out;                                  // (B, NPOINT, 3)
    float* out_feat = (float*)d_out + (size_t)BATCH * NPOINT * 3;     // (B, 128, NPOINT)

    float* feat_t = (float*)d_ws;                                     // (B, NPTS, NCH)

    hipLaunchKernelGGL(fps_tr_kernel, dim3(BATCH + BATCH * (NPTS / 64)), dim3(512), 0,
                       stream, xyz, new_xyz, feat, feat_t);
    hipLaunchKernelGGL(bq_mlp_kernel, dim3(BATCH * NPOINT / 4), dim3(256), 0, stream,
                       xyz, feat_t, new_xyz,
                       W1, b1, W2, b2, W3, b3, out_feat);
}